// Round 4
// baseline (127.531 us; speedup 1.0000x reference)
//
#include <hip/hip_runtime.h>
#include <math.h>

#define HID 512
#define IN_FEAT 342
#define OUTD 311
#define BATCH 256
#define KP0 352           // layer-0 padded K (11 chunks of 32)
#define XROW (IN_FEAT + 1)
#define NB 32
#define NTHR 512
#define NBLK 256          // exactly 1 block/CU

typedef unsigned short u16;
typedef short bf16x8 __attribute__((ext_vector_type(8)));
typedef float f32x4 __attribute__((ext_vector_type(4)));

__device__ __forceinline__ u16 f2bf_rne(float v) {
    unsigned int x = __float_as_uint(v);
    unsigned int r = (x + 0x7fffu + ((x >> 16) & 1u)) >> 16;
    return (u16)r;
}
__device__ __forceinline__ float bf2f(u16 u) {
    return __uint_as_float(((unsigned int)u) << 16);
}

__device__ __forceinline__ void split8(const float* __restrict__ src, bf16x8& hi, bf16x8& lo) {
#pragma unroll
    for (int j = 0; j < 8; j++) {
        u16 h = f2bf_rne(src[j]);
        hi[j] = (short)h;
        lo[j] = (short)f2bf_rne(src[j] - bf2f(h));
    }
}

struct Params {
    const float *x, *W0, *b0, *W1, *b1, *W2, *b2;
    u16 *hahi, *halo, *hbhi, *hblo;
    unsigned* bar;
    float* outp;
};

// shared union: h planes at fixed max stride (32*520 u16 per plane), acc overlay
union SharedU {
    u16 h[2][NB * 520];
    float acc[4][NB][17];
};

// ---- grid barrier: monotone counter, single-use per launch, re-zeroed by init kernel ----
// release fence -> agent-scope L2 writeback of this XCD's plain stores;
// acquire fence -> L2/L1 invalidate so cross-XCD reads don't hit stale poison (R1 bug fix).
__device__ __forceinline__ void gbar(unsigned* cnt, unsigned nblk) {
    __syncthreads();
    if (threadIdx.x == 0) {
        __builtin_amdgcn_fence(__ATOMIC_RELEASE, "agent");
        __hip_atomic_fetch_add(cnt, 1u, __ATOMIC_RELAXED, __HIP_MEMORY_SCOPE_AGENT);
        long spins = 0;
        while (__hip_atomic_load(cnt, __ATOMIC_RELAXED, __HIP_MEMORY_SCOPE_AGENT) < nblk) {
            __builtin_amdgcn_s_sleep(2);
            if (++spins > (1L << 26)) break;   // safety: fail as mismatch, not hang
        }
        __builtin_amdgcn_fence(__ATOMIC_ACQUIRE, "agent");
    }
    __syncthreads();
}

// ---- one layer phase (verified R3 body) ----
// out[b][o] = act( sum_s d_s(b) * ( sum_k W[s][o][k]*H[b][k] + bias[s][o] ) )
template<int KP, int KLDS, int MODE, int KW, int MW, int FINAL>
__device__ __forceinline__ void phase(SharedU& sm, int bx, int by, int tid,
    const float* __restrict__ W, const float* __restrict__ x,
    const u16* __restrict__ Hhi, const u16* __restrict__ Hlo,
    const float* __restrict__ bias, int Mb,
    u16* __restrict__ Ohi, u16* __restrict__ Olo, float* __restrict__ outp)
{
    const int b0 = bx * NB;
    const int o0 = by * 16;
    u16* h0 = &sm.h[0][0];
    u16* h1 = &sm.h[1][0];

    // ---- stage H tile (NB rows x KP, hi+lo) into LDS ----
    constexpr int CH = KP / 8;
    if constexpr (MODE == 0) {
        for (int idx = tid; idx < NB * CH; idx += NTHR) {
            int r = idx / CH, c = idx - r * CH;
            int k = c * 8;
            const float* xr = x + (size_t)(b0 + r) * XROW;
            float src[8];
#pragma unroll
            for (int j = 0; j < 8; j++) {
                int kk = k + j;
                src[j] = (kk < IN_FEAT) ? xr[kk] : 0.f;
            }
            bf16x8 hi, lo;
            split8(src, hi, lo);
            *reinterpret_cast<bf16x8*>(&h0[r * KLDS + k]) = hi;
            *reinterpret_cast<bf16x8*>(&h1[r * KLDS + k]) = lo;
        }
    } else {
        for (int idx = tid; idx < NB * CH; idx += NTHR) {
            int r = idx / CH, c = idx - r * CH;
            size_t g = (size_t)(b0 + r) * KP + c * 8;
            *reinterpret_cast<uint4*>(&h0[r * KLDS + c * 8]) =
                *reinterpret_cast<const uint4*>(Hhi + g);
            *reinterpret_cast<uint4*>(&h1[r * KLDS + c * 8]) =
                *reinterpret_cast<const uint4*>(Hlo + g);
        }
    }
    __syncthreads();

    const int lane = tid & 63;
    const int w = tid >> 6;
    const int s = w & 3;                      // slice
    const int t = w >> 2;                     // b-half
    const int m = lane & 15;
    const int q = lane >> 4;

    const int orow = o0 + m;
    const bool vrow = (MW == HID) ? true : (orow < MW);
    const float* wr = W + ((size_t)s * MW + (vrow ? orow : 0)) * KW;
    const u16* hp = &h0[(t * 16 + m) * KLDS + q * 8];
    const u16* hpl = &h1[(t * 16 + m) * KLDS + q * 8];

    // inline cubic blend coefficient d_s(b)
    const int brow = b0 + t * 16 + m;
    const float ps = 4.f * x[(size_t)brow * XROW + IN_FEAT];
    const float fl = floorf(ps);
    const float mu = ps - fl;
    const int i1 = ((int)fl) & 3;
    const int jj = (s - i1) & 3;
    const float mu2 = mu * mu, mu3 = mu2 * mu;
    const float ds = (jj == 0) ? ( 1.5f * mu3 - 2.5f * mu2 + 1.0f)
                   : (jj == 1) ? (-1.5f * mu3 + 2.0f * mu2 + 0.5f * mu)
                   : (jj == 2) ? ( 0.5f * mu3 - 0.5f * mu2)
                   :             (-0.5f * mu3 + mu2 - 0.5f * mu);

    f32x4 a0 = {0.f, 0.f, 0.f, 0.f};
    f32x4 a1 = {0.f, 0.f, 0.f, 0.f};
    f32x4 a2 = {0.f, 0.f, 0.f, 0.f};
#pragma unroll
    for (int cc = 0; cc < KP / 32; ++cc) {
        const int k0 = cc * 32 + q * 8;
        float ws[8];
        if (vrow && (cc * 32 + 32 <= KW)) {
            if constexpr (KW % 4 == 0) {
                const float4* p4 = reinterpret_cast<const float4*>(wr + k0);
                float4 v0 = p4[0], v1 = p4[1];
                ws[0] = v0.x; ws[1] = v0.y; ws[2] = v0.z; ws[3] = v0.w;
                ws[4] = v1.x; ws[5] = v1.y; ws[6] = v1.z; ws[7] = v1.w;
            } else {                           // KW=342: rows only 8B-aligned
                const float2* p2 = reinterpret_cast<const float2*>(wr + k0);
                float2 v0 = p2[0], v1 = p2[1], v2 = p2[2], v3 = p2[3];
                ws[0] = v0.x; ws[1] = v0.y; ws[2] = v1.x; ws[3] = v1.y;
                ws[4] = v2.x; ws[5] = v2.y; ws[6] = v3.x; ws[7] = v3.y;
            }
        } else {
#pragma unroll
            for (int j = 0; j < 8; j++) {
                int kk = k0 + j;
                ws[j] = (vrow && kk < KW) ? wr[kk] : 0.f;
            }
        }
        bf16x8 ah, al;
        split8(ws, ah, al);
        bf16x8 bh = *reinterpret_cast<const bf16x8*>(hp + cc * 32);
        bf16x8 bl = *reinterpret_cast<const bf16x8*>(hpl + cc * 32);
        a0 = __builtin_amdgcn_mfma_f32_16x16x32_bf16(ah, bh, a0, 0, 0, 0);
        a1 = __builtin_amdgcn_mfma_f32_16x16x32_bf16(ah, bl, a1, 0, 0, 0);
        a2 = __builtin_amdgcn_mfma_f32_16x16x32_bf16(al, bh, a2, 0, 0, 0);
    }
    __syncthreads();   // LDS H reads done; reuse union as blend buffer

    f32x4 sum = a0 + a1 + a2;
#pragma unroll
    for (int r = 0; r < 4; ++r) {
        int o = o0 + q * 4 + r;
        float bb = (o < Mb) ? bias[(size_t)s * Mb + o] : 0.f;
        sm.acc[s][t * 16 + m][q * 4 + r] = ds * (sum[r] + bb);
    }
    __syncthreads();

    const int b_l = tid >> 4;
    const int o_l = tid & 15;
    float vv = sm.acc[0][b_l][o_l] + sm.acc[1][b_l][o_l]
             + sm.acc[2][b_l][o_l] + sm.acc[3][b_l][o_l];
    const int o = o0 + o_l;
    const int b = b0 + b_l;
    if (!FINAL) {
        float e = (vv > 0.f) ? vv : expm1f(vv);
        u16 h = f2bf_rne(e);
        Ohi[(size_t)b * HID + o] = h;
        Olo[(size_t)b * HID + o] = f2bf_rne(e - bf2f(h));
    } else if (o < OUTD) {
        outp[(size_t)b * OUTD + o] = vv;
    }
}

// ---- init: zero barrier counters (workspace is re-poisoned every replay) ----
__global__ void zero_bar(unsigned* bar) {
    if (threadIdx.x < 128) bar[threadIdx.x] = 0u;
}

// ---- fused 3-layer kernel: 256 blocks x 512 thr, 2 internal grid barriers ----
// block decode: blk%8 == by%8 -> all 8 bx-duplicates of a weight tile on one XCD.
__global__ __launch_bounds__(NTHR, 1) void fused3(Params p) {
    __shared__ SharedU sm;
    const int blk = (int)blockIdx.x;
    const int tid = (int)threadIdx.x;
    const int bx = (blk >> 3) & 7;
    const int by = (blk & 7) | ((blk >> 6) << 3);

    // L0: K=352 (KW=342), M=512, H from x
    phase<KP0, 360, 0, IN_FEAT, HID, 0>(sm, bx, by, tid,
        p.W0, p.x, nullptr, nullptr, p.b0, HID, p.hahi, p.halo, nullptr);
    gbar(p.bar + 0, NBLK);

    // L1: K=512, M=512
    phase<HID, 520, 1, HID, HID, 0>(sm, bx, by, tid,
        p.W1, p.x, p.hahi, p.halo, p.b1, HID, p.hbhi, p.hblo, nullptr);
    gbar(p.bar + 64, NBLK);

    // L2: K=512, M=311 -> by < 20 active (all blocks passed both barriers)
    if (by < 20) {
        phase<HID, 520, 1, HID, OUTD, 1>(sm, bx, by, tid,
            p.W2, p.x, p.hbhi, p.hblo, p.b2, OUTD, nullptr, nullptr, p.outp);
    }
}

extern "C" void kernel_launch(void* const* d_in, const int* in_sizes, int n_in,
                              void* d_out, int out_size, void* d_ws, size_t ws_size,
                              hipStream_t stream) {
    Params p;
    p.x  = (const float*)d_in[0];
    p.W0 = (const float*)d_in[1];
    p.b0 = (const float*)d_in[2];
    p.W1 = (const float*)d_in[3];
    p.b1 = (const float*)d_in[4];
    p.W2 = (const float*)d_in[5];
    p.b2 = (const float*)d_in[6];
    p.outp = (float*)d_out;

    char* pw = (char*)d_ws;
    auto alloc = [&](size_t bytes) { char* r = pw; pw += (bytes + 255) & ~(size_t)255; return r; };

    p.bar  = (unsigned*)alloc(512);
    p.hahi = (u16*)alloc((size_t)BATCH * HID * 2);
    p.halo = (u16*)alloc((size_t)BATCH * HID * 2);
    p.hbhi = (u16*)alloc((size_t)BATCH * HID * 2);
    p.hblo = (u16*)alloc((size_t)BATCH * HID * 2);

    zero_bar<<<1, 128, 0, stream>>>(p.bar);
    fused3<<<NBLK, NTHR, 0, stream>>>(p);
}

// Round 5
// 113.144 us; speedup vs baseline: 1.1272x; 1.1272x over previous
//
#include <hip/hip_runtime.h>
#include <math.h>

#define HID 512
#define IN_FEAT 342
#define OUTD 311
#define BATCH 256
#define KP0 352           // layer-0 padded K (11 chunks of 32)
#define XROW (IN_FEAT + 1)
#define NB 32
#define NTHR 512

typedef unsigned short u16;
typedef short bf16x8 __attribute__((ext_vector_type(8)));
typedef float f32x4 __attribute__((ext_vector_type(4)));

__device__ __forceinline__ u16 f2bf_rne(float v) {
    unsigned int x = __float_as_uint(v);
    unsigned int r = (x + 0x7fffu + ((x >> 16) & 1u)) >> 16;
    return (u16)r;
}
__device__ __forceinline__ float bf2f(u16 u) {
    return __uint_as_float(((unsigned int)u) << 16);
}

__device__ __forceinline__ void split8(const float* __restrict__ src, bf16x8& hi, bf16x8& lo) {
#pragma unroll
    for (int j = 0; j < 8; j++) {
        u16 h = f2bf_rne(src[j]);
        hi[j] = (short)h;
        lo[j] = (short)f2bf_rne(src[j] - bf2f(h));
    }
}

// ======= fused layer, XCD-aware grid, FULL weight register-prefetch =======
// out[b][o] = act( sum_s d_s(b) * ( sum_k W[s][o][k]*H[b][k] + bias[s][o] ) )
// All weight chunks for the K-loop are issued as independent loads BEFORE the
// staging barrier; the compiler's vmcnt drain at __syncthreads pays ONE HBM
// latency for all of them (R4 counters showed ~1 chunk in flight -> serial
// 900-cyc round-trips; MfmaUtil 1.6%, BW 1.8% -> latency-bound).
// WARM=1 (L0 only): each thread streams 4 float4 of W1/W2 to pre-warm the LLC
// (poison fill evicts it every replay) so L1/L2 weight fetches are LLC hits.
// Invalid rows (MW<HID) load row 0 and produce garbage confined to output rows
// >= OUTD, which are never stored.
template<int KP, int KLDS, int FINAL, int MODE, int KW, int MW, int NBY, int WARM>
__global__ __launch_bounds__(NTHR, 2) void layer_pf(
    const float* __restrict__ W, const float* __restrict__ x,
    const u16* __restrict__ Hhi, const u16* __restrict__ Hlo,
    const float* __restrict__ bias, int Mb,
    u16* __restrict__ Ohi, u16* __restrict__ Olo, float* __restrict__ outp,
    const float* __restrict__ Wa, const float* __restrict__ Wb, int nbf4)
{
    union SharedU {
        u16 h[2][NB * KLDS];
        float acc[4][NB][17];
    };
    __shared__ SharedU sm;

    const int blk = (int)blockIdx.x;
    const int bx = (blk >> 3) & 7;
    const int by = (blk & 7) | ((blk >> 6) << 3);
    if (by >= NBY) return;                    // uniform per-block: no barrier hazard

    const int tid = (int)threadIdx.x;
    const int lane = tid & 63;
    const int w = tid >> 6;
    const int s = w & 3;                      // slice
    const int t = w >> 2;                     // b-half
    const int m = lane & 15;
    const int q = lane >> 4;
    const int b0 = bx * NB;
    const int o0 = by * 16;

    const int orow = o0 + m;
    const bool vrow = (MW == HID) ? true : (orow < MW);
    const float* wr = W + ((size_t)s * MW + (vrow ? orow : 0)) * KW;

    constexpr int NCC = KP / 32;              // K-loop steps
    constexpr int CCF = KW / 32;              // full 32-wide chunks (16 for 512, 10 for 342)

    // ---- issue ALL weight loads up-front (registers, statically indexed) ----
    float4 wv4[(KW % 4 == 0) ? 2 * CCF : 1];
    float2 wv2[(KW % 4 == 0) ? 1 : 4 * CCF];
    float wtail[8];
    if constexpr (KW % 4 == 0) {
        const float4* p4 = reinterpret_cast<const float4*>(wr + q * 8);
#pragma unroll
        for (int cc = 0; cc < CCF; ++cc) {
            wv4[2 * cc]     = p4[cc * 8];
            wv4[2 * cc + 1] = p4[cc * 8 + 1];
        }
    } else {                                   // KW=342: rows only 8B-aligned
        const float2* p2 = reinterpret_cast<const float2*>(wr + q * 8);
#pragma unroll
        for (int cc = 0; cc < CCF; ++cc) {
#pragma unroll
            for (int j = 0; j < 4; ++j) wv2[4 * cc + j] = p2[cc * 16 + j];
        }
#pragma unroll
        for (int j = 0; j < 8; ++j) {          // partial chunk cc=CCF, masked
            int kk = CCF * 32 + q * 8 + j;
            wtail[j] = (kk < KW) ? wr[kk] : 0.f;
        }
    }

    // ---- LLC warm of next layers' weights (L0 only) ----
    float wsum = 0.f;
    if constexpr (WARM) {
        const float4* wa = reinterpret_cast<const float4*>(Wa);
        const float4* wb = reinterpret_cast<const float4*>(Wb);
        int gi = blk * NTHR + tid;             // 131072 threads chip-wide
        float4 t0 = wa[gi];
        float4 t1 = wa[gi + 131072];           // W1: exactly 262144 float4
        float4 t2 = wb[gi];
        int gi2 = (gi + 131072 < nbf4) ? gi + 131072 : gi;
        float4 t3 = wb[gi2];
        wsum = t0.x + t0.y + t0.z + t0.w + t1.x + t1.y + t1.z + t1.w
             + t2.x + t2.y + t2.z + t2.w + t3.x + t3.y + t3.z + t3.w;
    }

    // ---- stage H tile (NB rows x KP, hi+lo) into LDS ----
    constexpr int CH = KP / 8;
    if constexpr (MODE == 0) {
        for (int idx = tid; idx < NB * CH; idx += NTHR) {
            int r = idx / CH, c = idx - r * CH;
            int k = c * 8;
            const float* xr = x + (size_t)(b0 + r) * XROW;
            float src[8];
#pragma unroll
            for (int j = 0; j < 8; j++) {
                int kk = k + j;
                src[j] = (kk < IN_FEAT) ? xr[kk] : 0.f;
            }
            bf16x8 hi, lo;
            split8(src, hi, lo);
            *reinterpret_cast<bf16x8*>(&sm.h[0][r * KLDS + k]) = hi;
            *reinterpret_cast<bf16x8*>(&sm.h[1][r * KLDS + k]) = lo;
        }
    } else {
        for (int idx = tid; idx < NB * CH; idx += NTHR) {
            int r = idx / CH, c = idx - r * CH;
            size_t g = (size_t)(b0 + r) * KP + c * 8;
            *reinterpret_cast<uint4*>(&sm.h[0][r * KLDS + c * 8]) =
                *reinterpret_cast<const uint4*>(Hhi + g);
            *reinterpret_cast<uint4*>(&sm.h[1][r * KLDS + c * 8]) =
                *reinterpret_cast<const uint4*>(Hlo + g);
        }
    }
    __syncthreads();

    const u16* hp  = &sm.h[0][(t * 16 + m) * KLDS + q * 8];
    const u16* hpl = &sm.h[1][(t * 16 + m) * KLDS + q * 8];

    // ---- inline cubic blend coefficient d_s(b) ----
    const int brow = b0 + t * 16 + m;
    const float ps = 4.f * x[(size_t)brow * XROW + IN_FEAT];
    const float fl = floorf(ps);
    const float mu = ps - fl;
    const int i1 = ((int)fl) & 3;
    const int jj = (s - i1) & 3;
    const float mu2 = mu * mu, mu3 = mu2 * mu;
    const float ds = (jj == 0) ? ( 1.5f * mu3 - 2.5f * mu2 + 1.0f)
                   : (jj == 1) ? (-1.5f * mu3 + 2.0f * mu2 + 0.5f * mu)
                   : (jj == 2) ? ( 0.5f * mu3 - 0.5f * mu2)
                   :             (-0.5f * mu3 + mu2 - 0.5f * mu);

    f32x4 a0 = {0.f, 0.f, 0.f, 0.f};
    f32x4 a1 = {0.f, 0.f, 0.f, 0.f};
    f32x4 a2 = {0.f, 0.f, 0.f, 0.f};
#pragma unroll
    for (int cc = 0; cc < NCC; ++cc) {
        float ws[8];
        if constexpr (KW % 4 == 0) {
            float4 v0 = wv4[2 * cc], v1 = wv4[2 * cc + 1];
            ws[0] = v0.x; ws[1] = v0.y; ws[2] = v0.z; ws[3] = v0.w;
            ws[4] = v1.x; ws[5] = v1.y; ws[6] = v1.z; ws[7] = v1.w;
        } else if (cc < CCF) {
            float2 v0 = wv2[4 * cc], v1 = wv2[4 * cc + 1];
            float2 v2 = wv2[4 * cc + 2], v3 = wv2[4 * cc + 3];
            ws[0] = v0.x; ws[1] = v0.y; ws[2] = v1.x; ws[3] = v1.y;
            ws[4] = v2.x; ws[5] = v2.y; ws[6] = v3.x; ws[7] = v3.y;
        } else {
#pragma unroll
            for (int j = 0; j < 8; ++j) ws[j] = wtail[j];
        }
        bf16x8 ah, al;
        split8(ws, ah, al);
        bf16x8 bh = *reinterpret_cast<const bf16x8*>(hp + cc * 32);
        bf16x8 bl = *reinterpret_cast<const bf16x8*>(hpl + cc * 32);
        a0 = __builtin_amdgcn_mfma_f32_16x16x32_bf16(ah, bh, a0, 0, 0, 0);
        a1 = __builtin_amdgcn_mfma_f32_16x16x32_bf16(ah, bl, a1, 0, 0, 0);
        a2 = __builtin_amdgcn_mfma_f32_16x16x32_bf16(al, bh, a2, 0, 0, 0);
    }
    __syncthreads();   // LDS H reads done; reuse union as blend buffer

    // wave-phase blend: d_s(b) * (sum + bias_s). C layout: col=lane&15 (b), row=q*4+r (o).
    f32x4 sum = a0 + a1 + a2;
#pragma unroll
    for (int r = 0; r < 4; ++r) {
        int o = o0 + q * 4 + r;
        float bb = (o < Mb) ? bias[(size_t)s * Mb + o] : 0.f;
        sm.acc[s][t * 16 + m][q * 4 + r] = ds * (sum[r] + bb);
    }
    __syncthreads();

    // reduce 4 slices, activate, store
    const int b_l = tid >> 4;
    const int o_l = tid & 15;
    float vv = sm.acc[0][b_l][o_l] + sm.acc[1][b_l][o_l]
             + sm.acc[2][b_l][o_l] + sm.acc[3][b_l][o_l];
    const int o = o0 + o_l;
    const int b = b0 + b_l;
    if (!FINAL) {
        float e = (vv > 0.f) ? vv : expm1f(vv);
        u16 h = f2bf_rne(e);
        Ohi[(size_t)b * HID + o] = h;
        Olo[(size_t)b * HID + o] = f2bf_rne(e - bf2f(h));
    } else if (o < OUTD) {
        outp[(size_t)b * OUTD + o] = vv;
    }

    if constexpr (WARM) {
        asm volatile("" :: "v"(wsum));        // keep warm loads live (rule #17)
    }
}

extern "C" void kernel_launch(void* const* d_in, const int* in_sizes, int n_in,
                              void* d_out, int out_size, void* d_ws, size_t ws_size,
                              hipStream_t stream) {
    const float* x  = (const float*)d_in[0];
    const float* W0 = (const float*)d_in[1];
    const float* b0v = (const float*)d_in[2];
    const float* W1 = (const float*)d_in[3];
    const float* b1v = (const float*)d_in[4];
    const float* W2 = (const float*)d_in[5];
    const float* b2v = (const float*)d_in[6];
    float* out = (float*)d_out;

    char* pw = (char*)d_ws;
    auto alloc = [&](size_t bytes) { char* r = pw; pw += (bytes + 255) & ~(size_t)255; return r; };

    u16* hahi = (u16*)alloc((size_t)BATCH * HID * 2);
    u16* halo = (u16*)alloc((size_t)BATCH * HID * 2);
    u16* hbhi = (u16*)alloc((size_t)BATCH * HID * 2);
    u16* hblo = (u16*)alloc((size_t)BATCH * HID * 2);

    // W2 float4 count for warm guard: 4*311*512/4 = 159232
    // L0: K=352 (KW=342), M=512, H from x; warms W1+W2 into LLC
    layer_pf<KP0, 360, 0, 0, IN_FEAT, HID, 32, 1><<<256, NTHR, 0, stream>>>(
        W0, x, nullptr, nullptr, b0v, HID, hahi, halo, nullptr, W1, W2, 159232);

    // L1: K=512, M=512
    layer_pf<HID, 520, 0, 1, HID, HID, 32, 0><<<256, NTHR, 0, stream>>>(
        W1, x, hahi, halo, b1v, HID, hbhi, hblo, nullptr, nullptr, nullptr, 0);

    // L2: K=512, M=311 (NBY=20) -> 192-block padded grid (160 active)
    layer_pf<HID, 520, 1, 1, HID, OUTD, 20, 0><<<192, NTHR, 0, stream>>>(
        W2, x, hbhi, hblo, b2v, OUTD, nullptr, nullptr, out, nullptr, nullptr, 0);
}

// Round 6
// 99.906 us; speedup vs baseline: 1.2765x; 1.1325x over previous
//
#include <hip/hip_runtime.h>
#include <math.h>

#define HID 512
#define IN_FEAT 342
#define OUTD 311
#define BATCH 256
#define KP0 352           // layer-0 padded K (11 chunks of 32)
#define XROW (IN_FEAT + 1)
#define NB 32
#define NTHR 512

// fragment-array geometry: [4 slices][NT o-tiles][NCC K-chunks][1024 u16]
// each 1024-u16 block = 512 hi + 512 lo; element (plane, lane, j) at plane*512 + lane*8 + j,
// lane = q*16 + m holds W[s][ot*16+m][cc*32+q*8+j].
#define NT0 32
#define NCC0 11
#define NT1 32
#define NCC1 16
#define NT2 20
#define NCC2 16

// prep item counts: one thread per (s, row, k-octet)
#define P0 (4 * 512 * 44)     // 90112
#define P1 (4 * 512 * 64)     // 131072
#define P2 (4 * 320 * 64)     // 81920 (rows >= 311 zero-filled)
#define PTOT (P0 + P1 + P2)   // 303104 = 1184 * 256

typedef unsigned short u16;
typedef short bf16x8 __attribute__((ext_vector_type(8)));
typedef float f32x4 __attribute__((ext_vector_type(4)));

__device__ __forceinline__ u16 f2bf_rne(float v) {
    unsigned int x = __float_as_uint(v);
    unsigned int r = (x + 0x7fffu + ((x >> 16) & 1u)) >> 16;
    return (u16)r;
}
__device__ __forceinline__ float bf2f(u16 u) {
    return __uint_as_float(((unsigned int)u) << 16);
}

union U8 { u16 u[8]; uint4 v; };

__device__ __forceinline__ void split8(const float* __restrict__ src, bf16x8& hi, bf16x8& lo) {
#pragma unroll
    for (int j = 0; j < 8; j++) {
        u16 h = f2bf_rne(src[j]);
        hi[j] = (short)h;
        lo[j] = (short)f2bf_rne(src[j] - bf2f(h));
    }
}

// ===== prep: W -> fragment-ordered bf16 hi/lo =====
// Reads are row-major coalesced (consecutive threads read consecutive 32B);
// writes scatter 16B but stores don't stall. Huge TLP (1184 blocks) hides latency.
__global__ __launch_bounds__(256) void prep_frag(
    const float* __restrict__ W0, const float* __restrict__ W1, const float* __restrict__ W2,
    u16* __restrict__ F0, u16* __restrict__ F1, u16* __restrict__ F2)
{
    int i = blockIdx.x * 256 + threadIdx.x;
    if (i >= PTOT) return;

    float src[8];
    u16* dst;
    if (i < P0) {                              // ---- W0: KW=342 -> 11 chunks ----
        int s = i / (512 * 44);
        int rem = i - s * (512 * 44);
        int row = rem / 44, c = rem - row * 44;
        int k = c * 8;
        const float* rp = W0 + ((size_t)s * 512 + row) * IN_FEAT;
        if (k + 8 <= IN_FEAT) {                // rows are 8B-aligned: float2 loads
            const float2* p2 = reinterpret_cast<const float2*>(rp + k);
            float2 v0 = p2[0], v1 = p2[1], v2 = p2[2], v3 = p2[3];
            src[0] = v0.x; src[1] = v0.y; src[2] = v1.x; src[3] = v1.y;
            src[4] = v2.x; src[5] = v2.y; src[6] = v3.x; src[7] = v3.y;
        } else {
#pragma unroll
            for (int j = 0; j < 8; j++) src[j] = (k + j < IN_FEAT) ? rp[k + j] : 0.f;
        }
        int ot = row >> 4, m = row & 15, cc = c >> 2, q = c & 3;
        dst = F0 + ((size_t)(s * NT0 + ot) * NCC0 + cc) * 1024 + (q * 16 + m) * 8;
    } else if (i < P0 + P1) {                  // ---- W1: 512x512 ----
        int l = i - P0;
        int s = l >> 15;                       // 512*64 = 32768
        int row = (l >> 6) & 511, c = l & 63;
        int k = c * 8;
        const float4* p4 = reinterpret_cast<const float4*>(
            W1 + ((size_t)s * 512 + row) * 512 + k);
        float4 v0 = p4[0], v1 = p4[1];
        src[0] = v0.x; src[1] = v0.y; src[2] = v0.z; src[3] = v0.w;
        src[4] = v1.x; src[5] = v1.y; src[6] = v1.z; src[7] = v1.w;
        int ot = row >> 4, m = row & 15, cc = c >> 2, q = c & 3;
        dst = F1 + ((size_t)(s * NT1 + ot) * NCC1 + cc) * 1024 + (q * 16 + m) * 8;
    } else {                                   // ---- W2: 311x512, pad rows to 320 ----
        int l = i - P0 - P1;
        int s = l / (320 * 64);
        int rem = l - s * (320 * 64);
        int row = rem >> 6, c = rem & 63;
        int k = c * 8;
        if (row < OUTD) {
            const float4* p4 = reinterpret_cast<const float4*>(
                W2 + ((size_t)s * OUTD + row) * 512 + k);
            float4 v0 = p4[0], v1 = p4[1];
            src[0] = v0.x; src[1] = v0.y; src[2] = v0.z; src[3] = v0.w;
            src[4] = v1.x; src[5] = v1.y; src[6] = v1.z; src[7] = v1.w;
        } else {
#pragma unroll
            for (int j = 0; j < 8; j++) src[j] = 0.f;
        }
        int ot = row >> 4, m = row & 15, cc = c >> 2, q = c & 3;
        dst = F2 + ((size_t)(s * NT2 + ot) * NCC2 + cc) * 1024 + (q * 16 + m) * 8;
    }

    U8 hi, lo;
#pragma unroll
    for (int j = 0; j < 8; j++) {
        u16 h = f2bf_rne(src[j]);
        hi.u[j] = h;
        lo.u[j] = f2bf_rne(src[j] - bf2f(h));
    }
    *reinterpret_cast<uint4*>(dst)       = hi.v;
    *reinterpret_cast<uint4*>(dst + 512) = lo.v;
}

// ===== fused layer with fragment-ordered W (coalesced 1KB wave-loads) =====
// out[b][o] = act( sum_s d_s(b) * ( sum_k W[s][o][k]*H[b][k] + bias[s][o] ) )
// H: MODE 0 = from x (convert during staging); MODE 1 = bf16 hi/lo buffers.
// dcoef inline per MFMA thread. XCD decode: blk%8 == by%8 -> weight-sharing
// blocks on one XCD. 8 waves: (slice s=w&3, b-half t=w>>2).
template<int KP, int KLDS, int FINAL, int MODE, int NT, int NBY>
__global__ __launch_bounds__(NTHR, 1) void layer_frag(
    const u16* __restrict__ Wf, const float* __restrict__ x,
    const u16* __restrict__ Hhi, const u16* __restrict__ Hlo,
    const float* __restrict__ bias, int Mb,
    u16* __restrict__ Ohi, u16* __restrict__ Olo, float* __restrict__ outp)
{
    union SharedU {
        u16 h[2][NB * KLDS];
        float acc[4][NB][17];
    };
    __shared__ SharedU sm;

    const int blk = (int)blockIdx.x;
    const int bx = (blk >> 3) & 7;
    const int by = (blk & 7) | ((blk >> 6) << 3);
    if (by >= NBY) return;                    // uniform per-block exit

    const int tid = (int)threadIdx.x;
    const int b0 = bx * NB;
    const int o0 = by * 16;

    // ---- stage H tile (NB rows x KP, hi+lo) into LDS ----
    constexpr int CH = KP / 8;
    if constexpr (MODE == 0) {
        for (int idx = tid; idx < NB * CH; idx += NTHR) {
            int r = idx / CH, c = idx - r * CH;
            int k = c * 8;
            const float* xr = x + (size_t)(b0 + r) * XROW;
            float src[8];
#pragma unroll
            for (int j = 0; j < 8; j++) {
                int kk = k + j;
                src[j] = (kk < IN_FEAT) ? xr[kk] : 0.f;
            }
            bf16x8 hi, lo;
            split8(src, hi, lo);
            *reinterpret_cast<bf16x8*>(&sm.h[0][r * KLDS + k]) = hi;
            *reinterpret_cast<bf16x8*>(&sm.h[1][r * KLDS + k]) = lo;
        }
    } else {
        for (int idx = tid; idx < NB * CH; idx += NTHR) {
            int r = idx / CH, c = idx - r * CH;
            size_t g = (size_t)(b0 + r) * KP + c * 8;
            *reinterpret_cast<uint4*>(&sm.h[0][r * KLDS + c * 8]) =
                *reinterpret_cast<const uint4*>(Hhi + g);
            *reinterpret_cast<uint4*>(&sm.h[1][r * KLDS + c * 8]) =
                *reinterpret_cast<const uint4*>(Hlo + g);
        }
    }
    __syncthreads();

    const int lane = tid & 63;
    const int w = tid >> 6;
    const int s = w & 3;                      // slice
    const int t = w >> 2;                     // b-half
    const int m = lane & 15;
    const int q = lane >> 4;

    constexpr int NCC = KP / 32;
    // coalesced fragment stream: wave's 64 lanes read one contiguous 1KB block
    const u16* wf = Wf + ((size_t)(s * NT + by) * NCC) * 1024 + lane * 8;
    const u16* hp  = &sm.h[0][(t * 16 + m) * KLDS + q * 8];
    const u16* hpl = &sm.h[1][(t * 16 + m) * KLDS + q * 8];

    // ---- inline cubic blend coefficient d_s(b) ----
    const int brow = b0 + t * 16 + m;
    const float ps = 4.f * x[(size_t)brow * XROW + IN_FEAT];
    const float fl = floorf(ps);
    const float mu = ps - fl;
    const int i1 = ((int)fl) & 3;
    const int jj = (s - i1) & 3;
    const float mu2 = mu * mu, mu3 = mu2 * mu;
    const float ds = (jj == 0) ? ( 1.5f * mu3 - 2.5f * mu2 + 1.0f)
                   : (jj == 1) ? (-1.5f * mu3 + 2.0f * mu2 + 0.5f * mu)
                   : (jj == 2) ? ( 0.5f * mu3 - 0.5f * mu2)
                   :             (-0.5f * mu3 + mu2 - 0.5f * mu);

    f32x4 a0 = {0.f, 0.f, 0.f, 0.f};
    f32x4 a1 = {0.f, 0.f, 0.f, 0.f};
    f32x4 a2 = {0.f, 0.f, 0.f, 0.f};
#pragma unroll
    for (int cc = 0; cc < NCC; ++cc) {
        bf16x8 ah = *reinterpret_cast<const bf16x8*>(wf + cc * 1024);
        bf16x8 al = *reinterpret_cast<const bf16x8*>(wf + cc * 1024 + 512);
        bf16x8 bh = *reinterpret_cast<const bf16x8*>(hp + cc * 32);
        bf16x8 bl = *reinterpret_cast<const bf16x8*>(hpl + cc * 32);
        a0 = __builtin_amdgcn_mfma_f32_16x16x32_bf16(ah, bh, a0, 0, 0, 0);
        a1 = __builtin_amdgcn_mfma_f32_16x16x32_bf16(ah, bl, a1, 0, 0, 0);
        a2 = __builtin_amdgcn_mfma_f32_16x16x32_bf16(al, bh, a2, 0, 0, 0);
    }
    __syncthreads();   // LDS H reads done; reuse union as blend buffer

    // wave-phase blend: d_s(b) * (sum + bias_s). C layout: col=lane&15 (b), row=q*4+r (o).
    f32x4 sum = a0 + a1 + a2;
#pragma unroll
    for (int r = 0; r < 4; ++r) {
        int o = o0 + q * 4 + r;
        float bb = (o < Mb) ? bias[(size_t)s * Mb + o] : 0.f;
        sm.acc[s][t * 16 + m][q * 4 + r] = ds * (sum[r] + bb);
    }
    __syncthreads();

    // reduce 4 slices, activate, store
    const int b_l = tid >> 4;
    const int o_l = tid & 15;
    float vv = sm.acc[0][b_l][o_l] + sm.acc[1][b_l][o_l]
             + sm.acc[2][b_l][o_l] + sm.acc[3][b_l][o_l];
    const int o = o0 + o_l;
    const int b = b0 + b_l;
    if (!FINAL) {
        float e = (vv > 0.f) ? vv : expm1f(vv);
        u16 h = f2bf_rne(e);
        Ohi[(size_t)b * HID + o] = h;
        Olo[(size_t)b * HID + o] = f2bf_rne(e - bf2f(h));
    } else if (o < OUTD) {
        outp[(size_t)b * OUTD + o] = vv;
    }
}

extern "C" void kernel_launch(void* const* d_in, const int* in_sizes, int n_in,
                              void* d_out, int out_size, void* d_ws, size_t ws_size,
                              hipStream_t stream) {
    const float* x  = (const float*)d_in[0];
    const float* W0 = (const float*)d_in[1];
    const float* b0v = (const float*)d_in[2];
    const float* W1 = (const float*)d_in[3];
    const float* b1v = (const float*)d_in[4];
    const float* W2 = (const float*)d_in[5];
    const float* b2v = (const float*)d_in[6];
    float* out = (float*)d_out;

    char* pw = (char*)d_ws;
    auto alloc = [&](size_t bytes) { char* r = pw; pw += (bytes + 255) & ~(size_t)255; return r; };

    u16* F0 = (u16*)alloc((size_t)4 * NT0 * NCC0 * 1024 * 2);
    u16* F1 = (u16*)alloc((size_t)4 * NT1 * NCC1 * 1024 * 2);
    u16* F2 = (u16*)alloc((size_t)4 * NT2 * NCC2 * 1024 * 2);
    u16* hahi = (u16*)alloc((size_t)BATCH * HID * 2);
    u16* halo = (u16*)alloc((size_t)BATCH * HID * 2);
    u16* hbhi = (u16*)alloc((size_t)BATCH * HID * 2);
    u16* hblo = (u16*)alloc((size_t)BATCH * HID * 2);

    prep_frag<<<PTOT / 256, 256, 0, stream>>>(W0, W1, W2, F0, F1, F2);

    // L0: K=352, M=512, H from x
    layer_frag<KP0, 360, 0, 0, NT0, 32><<<256, NTHR, 0, stream>>>(
        F0, x, nullptr, nullptr, b0v, HID, hahi, halo, nullptr);

    // L1: K=512, M=512
    layer_frag<HID, 520, 0, 1, NT1, 32><<<256, NTHR, 0, stream>>>(
        F1, x, hahi, halo, b1v, HID, hbhi, hblo, nullptr);

    // L2: K=512, M=311 (20 o-tiles) -> 192-block padded grid (160 active)
    layer_frag<HID, 520, 1, 1, NT2, 20><<<192, NTHR, 0, stream>>>(
        F2, x, hbhi, hblo, b2v, OUTD, nullptr, nullptr, out);
}

// Round 7
// 99.558 us; speedup vs baseline: 1.2810x; 1.0035x over previous
//
#include <hip/hip_runtime.h>
#include <math.h>

#define HID 512
#define IN_FEAT 342
#define OUTD 311
#define BATCH 256
#define KP0 352           // layer-0 padded K (11 chunks of 32)
#define XROW (IN_FEAT + 1)
#define NB 16             // batch rows per block
#define NTHR 256          // 4 waves: wave w = slice s

// fragment-array geometry: [4 slices][NT o-tiles][NCC K-chunks][1024 u16]
// chunk block = 512 hi + 512 lo u16; element (plane, lane, j) at plane*512 + lane*8 + j,
// lane = q*16 + m holds W[s][ot*16+m][cc*32+q*8+j].
#define NT0 32
#define NCC0 11
#define NT1 32
#define NCC1 16
#define NT2 20
#define NCC2 16

typedef unsigned short u16;
typedef short bf16x8 __attribute__((ext_vector_type(8)));
typedef float f32x4 __attribute__((ext_vector_type(4)));

__device__ __forceinline__ u16 f2bf_rne(float v) {
    unsigned int x = __float_as_uint(v);
    unsigned int r = (x + 0x7fffu + ((x >> 16) & 1u)) >> 16;
    return (u16)r;
}
__device__ __forceinline__ float bf2f(u16 u) {
    return __uint_as_float(((unsigned int)u) << 16);
}

union U8 { u16 u[8]; uint4 v; };

__device__ __forceinline__ void split8(const float* __restrict__ src, bf16x8& hi, bf16x8& lo) {
#pragma unroll
    for (int j = 0; j < 8; j++) {
        u16 h = f2bf_rne(src[j]);
        hi[j] = (short)h;
        lo[j] = (short)f2bf_rne(src[j] - bf2f(h));
    }
}

// ===== prep: W -> fragment-ordered bf16 hi/lo, BOTH sides coalesced via LDS =====
// One block per (layer, s, o-tile). Reads: row-major f32, coalesced. Fragment
// scatter happens in LDS (cheap); LDS -> global dump is linear 16B/thread
// wave-bursts (4KB), replacing R6's 16B global scatter.
__global__ __launch_bounds__(256) void prep_frag(
    const float* __restrict__ W0, const float* __restrict__ W1, const float* __restrict__ W2,
    u16* __restrict__ F0, u16* __restrict__ F1, u16* __restrict__ F2)
{
    __shared__ u16 fr[16 * 1024];   // 32 KB: up to 16 chunks x (512 hi + 512 lo)
    const int bid = (int)blockIdx.x;
    const int tid = (int)threadIdx.x;

    if (bid < 128) {                       // ---- W0: s=bid>>5, ot=bid&31, NCC=11 ----
        const int s = bid >> 5, ot = bid & 31;
        for (int idx = tid; idx < 16 * 44; idx += 256) {
            int rr = idx / 44, c = idx - rr * 44;
            int k = c * 8;
            const float* rp = W0 + (size_t)(s * 512 + ot * 16 + rr) * IN_FEAT;
            float src[8];
            if (k + 8 <= IN_FEAT) {        // rows 8B-aligned: float2 loads
                const float2* p2 = reinterpret_cast<const float2*>(rp + k);
                float2 v0 = p2[0], v1 = p2[1], v2 = p2[2], v3 = p2[3];
                src[0] = v0.x; src[1] = v0.y; src[2] = v1.x; src[3] = v1.y;
                src[4] = v2.x; src[5] = v2.y; src[6] = v3.x; src[7] = v3.y;
            } else {
#pragma unroll
                for (int j = 0; j < 8; j++) src[j] = (k + j < IN_FEAT) ? rp[k + j] : 0.f;
            }
            U8 hi, lo;
#pragma unroll
            for (int j = 0; j < 8; j++) {
                u16 h = f2bf_rne(src[j]);
                hi.u[j] = h;
                lo.u[j] = f2bf_rne(src[j] - bf2f(h));
            }
            int cc = c >> 2, lane = (c & 3) * 16 + rr;
            *reinterpret_cast<uint4*>(&fr[cc * 1024 + lane * 8])       = hi.v;
            *reinterpret_cast<uint4*>(&fr[cc * 1024 + 512 + lane * 8]) = lo.v;
        }
        __syncthreads();
        uint4* dst = reinterpret_cast<uint4*>(F0 + (size_t)(s * NT0 + ot) * NCC0 * 1024);
        const uint4* srcp = reinterpret_cast<const uint4*>(fr);
        for (int idx = tid; idx < NCC0 * 128; idx += 256) dst[idx] = srcp[idx];
    } else if (bid < 256) {                // ---- W1: 512x512, NCC=16 ----
        const int l = bid - 128;
        const int s = l >> 5, ot = l & 31;
        for (int idx = tid; idx < 16 * 64; idx += 256) {
            int rr = idx >> 6, c = idx & 63;
            const float4* p4 = reinterpret_cast<const float4*>(
                W1 + (size_t)(s * 512 + ot * 16 + rr) * 512 + c * 8);
            float4 v0 = p4[0], v1 = p4[1];
            float src[8] = {v0.x, v0.y, v0.z, v0.w, v1.x, v1.y, v1.z, v1.w};
            U8 hi, lo;
#pragma unroll
            for (int j = 0; j < 8; j++) {
                u16 h = f2bf_rne(src[j]);
                hi.u[j] = h;
                lo.u[j] = f2bf_rne(src[j] - bf2f(h));
            }
            int cc = c >> 2, lane = (c & 3) * 16 + rr;
            *reinterpret_cast<uint4*>(&fr[cc * 1024 + lane * 8])       = hi.v;
            *reinterpret_cast<uint4*>(&fr[cc * 1024 + 512 + lane * 8]) = lo.v;
        }
        __syncthreads();
        uint4* dst = reinterpret_cast<uint4*>(F1 + (size_t)(s * NT1 + ot) * NCC1 * 1024);
        const uint4* srcp = reinterpret_cast<const uint4*>(fr);
        for (int idx = tid; idx < NCC1 * 128; idx += 256) dst[idx] = srcp[idx];
    } else {                               // ---- W2: 311x512 pad to 320, NCC=16 ----
        const int l = bid - 256;
        const int s = l / 20, ot = l - s * 20;
        for (int idx = tid; idx < 16 * 64; idx += 256) {
            int rr = idx >> 6, c = idx & 63;
            int orow = ot * 16 + rr;
            float src[8] = {0.f, 0.f, 0.f, 0.f, 0.f, 0.f, 0.f, 0.f};
            if (orow < OUTD) {
                const float4* p4 = reinterpret_cast<const float4*>(
                    W2 + ((size_t)s * OUTD + orow) * 512 + c * 8);
                float4 v0 = p4[0], v1 = p4[1];
                src[0] = v0.x; src[1] = v0.y; src[2] = v0.z; src[3] = v0.w;
                src[4] = v1.x; src[5] = v1.y; src[6] = v1.z; src[7] = v1.w;
            }
            U8 hi, lo;
#pragma unroll
            for (int j = 0; j < 8; j++) {
                u16 h = f2bf_rne(src[j]);
                hi.u[j] = h;
                lo.u[j] = f2bf_rne(src[j] - bf2f(h));
            }
            int cc = c >> 2, lane = (c & 3) * 16 + rr;
            *reinterpret_cast<uint4*>(&fr[cc * 1024 + lane * 8])       = hi.v;
            *reinterpret_cast<uint4*>(&fr[cc * 1024 + 512 + lane * 8]) = lo.v;
        }
        __syncthreads();
        uint4* dst = reinterpret_cast<uint4*>(F2 + (size_t)(s * NT2 + ot) * NCC2 * 1024);
        const uint4* srcp = reinterpret_cast<const uint4*>(fr);
        for (int idx = tid; idx < NCC2 * 128; idx += 256) dst[idx] = srcp[idx];
    }
}

// ===== layer: NB=16, 256 thr, 4 waves (wave = slice), 2+ blocks/CU =====
// out[b][o] = act( sum_s d_s(b) * ( sum_k W[s][o][k]*H[b][k] + bias[s][o] ) )
// Fragment weights: wave reads contiguous 1KB blocks, sequential in cc.
// Decode: bx=(blk>>3)&15, by=(blk&7)|((blk>>7)<<3) -> blk%8 == by%8 (all 16
// batch-duplicates of one weight tile on one XCD). Small blocks -> 2 blocks/CU
// co-resident: one block's staging/epilogue overlaps the other's K-loop.
template<int KP, int KLDS, int FINAL, int MODE, int NT, int NBY>
__global__ __launch_bounds__(NTHR, 4) void layer_frag(
    const u16* __restrict__ Wf, const float* __restrict__ x,
    const u16* __restrict__ Hhi, const u16* __restrict__ Hlo,
    const float* __restrict__ bias, int Mb,
    u16* __restrict__ Ohi, u16* __restrict__ Olo, float* __restrict__ outp)
{
    union SharedU {
        u16 h[2][NB * KLDS];
        float acc[4][NB][17];
    };
    __shared__ SharedU sm;

    const int blk = (int)blockIdx.x;
    const int bx = (blk >> 3) & 15;
    const int by = (blk & 7) | ((blk >> 7) << 3);
    if (by >= NBY) return;                    // uniform per-block exit

    const int tid = (int)threadIdx.x;
    const int b0 = bx * NB;
    const int o0 = by * 16;

    // ---- stage H tile (NB rows x KP, hi+lo) into LDS ----
    constexpr int CH = KP / 8;
    if constexpr (MODE == 0) {
        for (int idx = tid; idx < NB * CH; idx += NTHR) {
            int r = idx / CH, c = idx - r * CH;
            int k = c * 8;
            const float* xr = x + (size_t)(b0 + r) * XROW;
            float src[8];
#pragma unroll
            for (int j = 0; j < 8; j++) {
                int kk = k + j;
                src[j] = (kk < IN_FEAT) ? xr[kk] : 0.f;
            }
            bf16x8 hi, lo;
            split8(src, hi, lo);
            *reinterpret_cast<bf16x8*>(&sm.h[0][r * KLDS + k]) = hi;
            *reinterpret_cast<bf16x8*>(&sm.h[1][r * KLDS + k]) = lo;
        }
    } else {
        for (int idx = tid; idx < NB * CH; idx += NTHR) {
            int r = idx / CH, c = idx - r * CH;
            size_t g = (size_t)(b0 + r) * KP + c * 8;
            *reinterpret_cast<uint4*>(&sm.h[0][r * KLDS + c * 8]) =
                *reinterpret_cast<const uint4*>(Hhi + g);
            *reinterpret_cast<uint4*>(&sm.h[1][r * KLDS + c * 8]) =
                *reinterpret_cast<const uint4*>(Hlo + g);
        }
    }
    __syncthreads();

    const int lane = tid & 63;
    const int s = tid >> 6;                   // wave = slice
    const int m = lane & 15;
    const int q = lane >> 4;

    constexpr int NCC = KP / 32;
    const u16* wf = Wf + ((size_t)(s * NT + by) * NCC) * 1024 + lane * 8;
    const u16* hp  = &sm.h[0][m * KLDS + q * 8];
    const u16* hpl = &sm.h[1][m * KLDS + q * 8];

    // ---- inline cubic blend coefficient d_s(b) ----
    const int brow = b0 + m;
    const float ps = 4.f * x[(size_t)brow * XROW + IN_FEAT];
    const float fl = floorf(ps);
    const float mu = ps - fl;
    const int i1 = ((int)fl) & 3;
    const int jj = (s - i1) & 3;
    const float mu2 = mu * mu, mu3 = mu2 * mu;
    const float ds = (jj == 0) ? ( 1.5f * mu3 - 2.5f * mu2 + 1.0f)
                   : (jj == 1) ? (-1.5f * mu3 + 2.0f * mu2 + 0.5f * mu)
                   : (jj == 2) ? ( 0.5f * mu3 - 0.5f * mu2)
                   :             (-0.5f * mu3 + mu2 - 0.5f * mu);

    f32x4 a0 = {0.f, 0.f, 0.f, 0.f};
    f32x4 a1 = {0.f, 0.f, 0.f, 0.f};
    f32x4 a2 = {0.f, 0.f, 0.f, 0.f};
#pragma unroll
    for (int cc = 0; cc < NCC; ++cc) {
        bf16x8 ah = *reinterpret_cast<const bf16x8*>(wf + cc * 1024);
        bf16x8 al = *reinterpret_cast<const bf16x8*>(wf + cc * 1024 + 512);
        bf16x8 bh = *reinterpret_cast<const bf16x8*>(hp + cc * 32);
        bf16x8 bl = *reinterpret_cast<const bf16x8*>(hpl + cc * 32);
        a0 = __builtin_amdgcn_mfma_f32_16x16x32_bf16(ah, bh, a0, 0, 0, 0);
        a1 = __builtin_amdgcn_mfma_f32_16x16x32_bf16(ah, bl, a1, 0, 0, 0);
        a2 = __builtin_amdgcn_mfma_f32_16x16x32_bf16(al, bh, a2, 0, 0, 0);
    }
    __syncthreads();   // LDS H reads done; reuse union as blend buffer

    // wave-phase blend: d_s(b) * (sum + bias_s). C layout: col=lane&15 (b), row=q*4+r (o).
    f32x4 sum = a0 + a1 + a2;
#pragma unroll
    for (int r = 0; r < 4; ++r) {
        int o = o0 + q * 4 + r;
        float bb = (o < Mb) ? bias[(size_t)s * Mb + o] : 0.f;
        sm.acc[s][m][q * 4 + r] = ds * (sum[r] + bb);
    }
    __syncthreads();

    // reduce 4 slices, activate, store: thread -> (b_l = tid>>4, o_l = tid&15)
    const int b_l = tid >> 4;
    const int o_l = tid & 15;
    float vv = sm.acc[0][b_l][o_l] + sm.acc[1][b_l][o_l]
             + sm.acc[2][b_l][o_l] + sm.acc[3][b_l][o_l];
    const int o = o0 + o_l;
    const int b = b0 + b_l;
    if (!FINAL) {
        float e = (vv > 0.f) ? vv : expm1f(vv);
        u16 h = f2bf_rne(e);
        Ohi[(size_t)b * HID + o] = h;
        Olo[(size_t)b * HID + o] = f2bf_rne(e - bf2f(h));
    } else if (o < OUTD) {
        outp[(size_t)b * OUTD + o] = vv;
    }
}

extern "C" void kernel_launch(void* const* d_in, const int* in_sizes, int n_in,
                              void* d_out, int out_size, void* d_ws, size_t ws_size,
                              hipStream_t stream) {
    const float* x  = (const float*)d_in[0];
    const float* W0 = (const float*)d_in[1];
    const float* b0v = (const float*)d_in[2];
    const float* W1 = (const float*)d_in[3];
    const float* b1v = (const float*)d_in[4];
    const float* W2 = (const float*)d_in[5];
    const float* b2v = (const float*)d_in[6];
    float* out = (float*)d_out;

    char* pw = (char*)d_ws;
    auto alloc = [&](size_t bytes) { char* r = pw; pw += (bytes + 255) & ~(size_t)255; return r; };

    u16* F0 = (u16*)alloc((size_t)4 * NT0 * NCC0 * 1024 * 2);
    u16* F1 = (u16*)alloc((size_t)4 * NT1 * NCC1 * 1024 * 2);
    u16* F2 = (u16*)alloc((size_t)4 * NT2 * NCC2 * 1024 * 2);
    u16* hahi = (u16*)alloc((size_t)BATCH * HID * 2);
    u16* halo = (u16*)alloc((size_t)BATCH * HID * 2);
    u16* hbhi = (u16*)alloc((size_t)BATCH * HID * 2);
    u16* hblo = (u16*)alloc((size_t)BATCH * HID * 2);

    prep_frag<<<336, 256, 0, stream>>>(W0, W1, W2, F0, F1, F2);

    // L0: K=352, M=512, H from x -> 16x32 = 512 blocks, 256 thr
    layer_frag<KP0, 360, 0, 0, NT0, 32><<<512, NTHR, 0, stream>>>(
        F0, x, nullptr, nullptr, b0v, HID, hahi, halo, nullptr);

    // L1: K=512, M=512 -> 512 blocks
    layer_frag<HID, 520, 0, 1, NT1, 32><<<512, NTHR, 0, stream>>>(
        F1, x, hahi, halo, b1v, HID, hbhi, hblo, nullptr);

    // L2: K=512, M=311 (20 o-tiles) -> 384-block padded grid (320 active)
    layer_frag<HID, 520, 1, 1, NT2, 20><<<384, NTHR, 0, stream>>>(
        F2, x, hbhi, hblo, b2v, OUTD, nullptr, nullptr, out);
}